// Round 1
// baseline (323.025 us; speedup 1.0000x reference)
//
#include <hip/hip_runtime.h>
#include <cmath>

namespace {

constexpr int kB    = 8;
constexpr int kH    = 160;
constexpr int kW    = 160;
constexpr int kC    = 256;
constexpr int kN    = 1024;
constexpr int kCrop = 14;
constexpr int kPO   = 7;                     // pooled output is 7x7
constexpr int kOutPos = kN * kPO * kPO;      // 50176 pooled positions

// One wave (64 lanes) per pooled output position; lane handles 4 channels
// (float4). 256-thread block = 4 waves = 4 pooled outputs.
__global__ __launch_bounds__(256) void roi_pool_kernel(
    const float* __restrict__ img,     // [B,H,W,C] NHWC
    const float* __restrict__ rois,    // [N,5]  (img_id, x0, y0, x1, y1)
    const float* __restrict__ iminfo,  // [N,2]  (H_img, W_img)
    float* __restrict__ out)           // [N,7,7,C]
{
    const int wave = threadIdx.x >> 6;
    const int lane = threadIdx.x & 63;
    const int p = blockIdx.x * 4 + wave;       // pooled position, exact grid
    const int n  = p / (kPO * kPO);
    const int r  = p - n * (kPO * kPO);
    const int ph = r / kPO;
    const int pw = r - ph * kPO;

    // Per-ROI scalars (wave-uniform; computed redundantly per lane)
    const float bidf = rois[n * 5 + 0];
    const float bx0  = rois[n * 5 + 1];
    const float by0  = rois[n * 5 + 2];
    const float bx1  = rois[n * 5 + 3];
    const float by1  = rois[n * 5 + 4];
    const float him  = iminfo[n * 2 + 0];
    const float wim  = iminfo[n * 2 + 1];
    const int b = (int)bidf;

    // Normalized box, reordered to [y1,x1,y2,x2] as in the reference
    const float y1 = by0 / him;
    const float x1 = bx0 / wim;
    const float y2 = by1 / him;
    const float x2 = bx1 / wim;

    const float ybase = y1 * (float)(kH - 1);
    const float xbase = x1 * (float)(kW - 1);
    // match reference op order: ((y2-y1)*(Hf-1))/(ch-1)
    const float ystep = ((y2 - y1) * (float)(kH - 1)) / (float)(kCrop - 1);
    const float xstep = ((x2 - x1) * (float)(kW - 1)) / (float)(kCrop - 1);

    float ylerp[2], xlerp[2];
    int   yl[2], yh[2], xl[2], xh[2];
    bool  vy[2], vx[2];
#pragma unroll
    for (int s = 0; s < 2; ++s) {
        const float y = ybase + (float)(2 * ph + s) * ystep;
        vy[s] = (y >= 0.0f) && (y <= (float)(kH - 1));
        const float yf = floorf(y);
        ylerp[s] = y - yf;
        yl[s] = (int)fminf(fmaxf(yf, 0.0f), (float)(kH - 1));
        yh[s] = (int)fminf(fmaxf(yf + 1.0f, 0.0f), (float)(kH - 1));

        const float x = xbase + (float)(2 * pw + s) * xstep;
        vx[s] = (x >= 0.0f) && (x <= (float)(kW - 1));
        const float xf = floorf(x);
        xlerp[s] = x - xf;
        xl[s] = (int)fminf(fmaxf(xf, 0.0f), (float)(kW - 1));
        xh[s] = (int)fminf(fmaxf(xf + 1.0f, 0.0f), (float)(kW - 1));
    }

    const int c = lane * 4;                               // channel offset
    const float* imgb = img + (size_t)b * (size_t)(kH * kW * kC);

    float4 acc = make_float4(-INFINITY, -INFINITY, -INFINITY, -INFINITY);
#pragma unroll
    for (int sy = 0; sy < 2; ++sy) {
#pragma unroll
        for (int sx = 0; sx < 2; ++sx) {
            float4 v = make_float4(0.0f, 0.0f, 0.0f, 0.0f);
            if (vy[sy] && vx[sx]) {                       // wave-uniform branch
                const float* rl = imgb + (size_t)yl[sy] * (kW * kC);
                const float* rh = imgb + (size_t)yh[sy] * (kW * kC);
                const float4 tl = *(const float4*)(rl + xl[sx] * kC + c);
                const float4 tr = *(const float4*)(rl + xh[sx] * kC + c);
                const float4 bl = *(const float4*)(rh + xl[sx] * kC + c);
                const float4 br = *(const float4*)(rh + xh[sx] * kC + c);
                const float xw = xlerp[sx];
                const float yw = ylerp[sy];
                const float t0 = tl.x + (tr.x - tl.x) * xw;
                const float t1 = tl.y + (tr.y - tl.y) * xw;
                const float t2 = tl.z + (tr.z - tl.z) * xw;
                const float t3 = tl.w + (tr.w - tl.w) * xw;
                const float b0 = bl.x + (br.x - bl.x) * xw;
                const float b1 = bl.y + (br.y - bl.y) * xw;
                const float b2 = bl.z + (br.z - bl.z) * xw;
                const float b3 = bl.w + (br.w - bl.w) * xw;
                v.x = t0 + (b0 - t0) * yw;
                v.y = t1 + (b1 - t1) * yw;
                v.z = t2 + (b2 - t2) * yw;
                v.w = t3 + (b3 - t3) * yw;
            }
            acc.x = fmaxf(acc.x, v.x);
            acc.y = fmaxf(acc.y, v.y);
            acc.z = fmaxf(acc.z, v.z);
            acc.w = fmaxf(acc.w, v.w);
        }
    }

    *(float4*)(out + (size_t)p * kC + c) = acc;
}

} // namespace

extern "C" void kernel_launch(void* const* d_in, const int* in_sizes, int n_in,
                              void* d_out, int out_size, void* d_ws, size_t ws_size,
                              hipStream_t stream) {
    const float* img    = (const float*)d_in[0];   // (8,160,160,256) f32
    const float* rois   = (const float*)d_in[1];   // (1024,5) f32
    const float* iminfo = (const float*)d_in[2];   // (1024,2) f32
    float* out = (float*)d_out;                    // (1024,7,7,256) f32

    dim3 grid(kOutPos / 4);   // 12544 blocks, 4 pooled outputs each
    dim3 block(256);
    roi_pool_kernel<<<grid, block, 0, stream>>>(img, rois, iminfo, out);
}

// Round 3
// 312.940 us; speedup vs baseline: 1.0322x; 1.0322x over previous
//
#include <hip/hip_runtime.h>
#include <cmath>

namespace {

constexpr int kB    = 8;
constexpr int kH    = 160;
constexpr int kW    = 160;
constexpr int kC    = 256;
constexpr int kN    = 1024;
constexpr int kCrop = 14;
constexpr int kPO   = 7;                     // pooled output is 7x7
constexpr int kOutPos = kN * kPO * kPO;      // 50176 pooled positions
constexpr int kBlocks = kOutPos / 4;         // 12544 (divisible by 8)

// One wave (64 lanes) per pooled output position; lane handles 4 channels
// (float4). 256-thread block = 4 waves = 4 pooled outputs.
//
// XCD swizzle: the CP dispatches blockIdx round-robin over the 8 XCDs
// (blockIdx % 8). Remap so each XCD receives a CONTIGUOUS run of logical
// blocks -> all ~13 blocks of one ROI share an XCD -> the ROI's ~3x
// column-reuse hits the 4 MB per-XCD L2 instead of falling to L3.
__global__ __launch_bounds__(256) void roi_pool_kernel(
    const float* __restrict__ img,     // [B,H,W,C] NHWC
    const float* __restrict__ rois,    // [N,5]  (img_id, x0, y0, x1, y1)
    const float* __restrict__ iminfo,  // [N,2]  (H_img, W_img)
    float* __restrict__ out)           // [N,7,7,C]
{
    const int wave = threadIdx.x >> 6;
    const int lane = threadIdx.x & 63;

    // physical -> logical block remap (XCD-contiguous)
    const int xcd = blockIdx.x & 7;
    const int lb  = xcd * (kBlocks >> 3) + (blockIdx.x >> 3);

    const int p = lb * 4 + wave;               // pooled position
    const int n  = p / (kPO * kPO);
    const int r  = p - n * (kPO * kPO);
    const int ph = r / kPO;
    const int pw = r - ph * kPO;

    // Per-ROI scalars (wave-uniform; computed redundantly per lane)
    const float bidf = rois[n * 5 + 0];
    const float bx0  = rois[n * 5 + 1];
    const float by0  = rois[n * 5 + 2];
    const float bx1  = rois[n * 5 + 3];
    const float by1  = rois[n * 5 + 4];
    const float him  = iminfo[n * 2 + 0];
    const float wim  = iminfo[n * 2 + 1];
    const int b = (int)bidf;

    const float y1 = by0 / him;
    const float x1 = bx0 / wim;
    const float y2 = by1 / him;
    const float x2 = bx1 / wim;

    const float ybase = y1 * (float)(kH - 1);
    const float xbase = x1 * (float)(kW - 1);
    const float ystep = ((y2 - y1) * (float)(kH - 1)) / (float)(kCrop - 1);
    const float xstep = ((x2 - x1) * (float)(kW - 1)) / (float)(kCrop - 1);

    float ylerp[2], xlerp[2];
    int   yl[2], yh[2], xl[2], xh[2];
    float vy[2], vx[2];
#pragma unroll
    for (int s = 0; s < 2; ++s) {
        const float y = ybase + (float)(2 * ph + s) * ystep;
        vy[s] = ((y >= 0.0f) && (y <= (float)(kH - 1))) ? 1.0f : 0.0f;
        const float yf = floorf(y);
        ylerp[s] = y - yf;
        yl[s] = (int)fminf(fmaxf(yf, 0.0f), (float)(kH - 1));
        yh[s] = (int)fminf(fmaxf(yf + 1.0f, 0.0f), (float)(kH - 1));

        const float x = xbase + (float)(2 * pw + s) * xstep;
        vx[s] = ((x >= 0.0f) && (x <= (float)(kW - 1))) ? 1.0f : 0.0f;
        const float xf = floorf(x);
        xlerp[s] = x - xf;
        xl[s] = (int)fminf(fmaxf(xf, 0.0f), (float)(kW - 1));
        xh[s] = (int)fminf(fmaxf(xf + 1.0f, 0.0f), (float)(kW - 1));
    }

    const int c = lane * 4;                               // channel offset
    const float* imgb = img + (size_t)b * (size_t)(kH * kW * kC) + c;

    // ---- issue all 16 corner loads before any math (max MLP) ----
    const float4* ptr[16];
#pragma unroll
    for (int sy = 0; sy < 2; ++sy) {
#pragma unroll
        for (int sx = 0; sx < 2; ++sx) {
            const int k = (sy * 2 + sx) * 4;
            const float* rl  = imgb + yl[sy] * (kW * kC);
            const float* rht = imgb + yh[sy] * (kW * kC);
            ptr[k + 0] = (const float4*)(rl  + xl[sx] * kC);
            ptr[k + 1] = (const float4*)(rl  + xh[sx] * kC);
            ptr[k + 2] = (const float4*)(rht + xl[sx] * kC);
            ptr[k + 3] = (const float4*)(rht + xh[sx] * kC);
        }
    }
    float4 d[16];
#pragma unroll
    for (int i = 0; i < 16; ++i) d[i] = *ptr[i];

    // acc MUST start at -INF: an all-valid window of negatives must yield the
    // negative max (invalid samples contribute literal 0 via the mask, which
    // then participates in the max — matching reference where+reduce_window).
    float4 acc = make_float4(-INFINITY, -INFINITY, -INFINITY, -INFINITY);
#pragma unroll
    for (int sy = 0; sy < 2; ++sy) {
#pragma unroll
        for (int sx = 0; sx < 2; ++sx) {
            const int k = (sy * 2 + sx) * 4;
            const float4 tl = d[k + 0];
            const float4 tr = d[k + 1];
            const float4 bl = d[k + 2];
            const float4 br = d[k + 3];
            const float xw = xlerp[sx];
            const float yw = ylerp[sy];
            const float m  = vy[sy] * vx[sx];   // 0 or 1
            const float t0 = tl.x + (tr.x - tl.x) * xw;
            const float t1 = tl.y + (tr.y - tl.y) * xw;
            const float t2 = tl.z + (tr.z - tl.z) * xw;
            const float t3 = tl.w + (tr.w - tl.w) * xw;
            const float b0 = bl.x + (br.x - bl.x) * xw;
            const float b1 = bl.y + (br.y - bl.y) * xw;
            const float b2 = bl.z + (br.z - bl.z) * xw;
            const float b3 = bl.w + (br.w - bl.w) * xw;
            acc.x = fmaxf(acc.x, (t0 + (b0 - t0) * yw) * m);
            acc.y = fmaxf(acc.y, (t1 + (b1 - t1) * yw) * m);
            acc.z = fmaxf(acc.z, (t2 + (b2 - t2) * yw) * m);
            acc.w = fmaxf(acc.w, (t3 + (b3 - t3) * yw) * m);
        }
    }

    // nontemporal: don't let the 51 MB output stream evict the gather
    // working set from L2
    float4* op = (float4*)(out + (size_t)p * kC + c);
    __builtin_nontemporal_store(acc.x, &op->x);
    __builtin_nontemporal_store(acc.y, &op->y);
    __builtin_nontemporal_store(acc.z, &op->z);
    __builtin_nontemporal_store(acc.w, &op->w);
}

} // namespace

extern "C" void kernel_launch(void* const* d_in, const int* in_sizes, int n_in,
                              void* d_out, int out_size, void* d_ws, size_t ws_size,
                              hipStream_t stream) {
    const float* img    = (const float*)d_in[0];   // (8,160,160,256) f32
    const float* rois   = (const float*)d_in[1];   // (1024,5) f32
    const float* iminfo = (const float*)d_in[2];   // (1024,2) f32
    float* out = (float*)d_out;                    // (1024,7,7,256) f32

    dim3 grid(kBlocks);   // 12544 blocks, 4 pooled outputs each
    dim3 block(256);
    roi_pool_kernel<<<grid, block, 0, stream>>>(img, rois, iminfo, out);
}